// Round 5
// baseline (544.571 us; speedup 1.0000x reference)
//
#include <hip/hip_runtime.h>
#include <cmath>

// INGP hashgrid encode — single fused kernel.
//   Level pinned per XCD (blockIdx%8; phase2 lvl=15-k balances cost) so each
//   XCD's 4MiB L2 holds its level's 4MiB table; gathers are L2-bound at
//   ~16 lines/cy/XCD (R3/R4 evidence: 274us ~ 80% of that floor; L1 bypass
//   regressed -> keep L1 in path). Output stored directly strided
//   (out[p*16+l]); per-XCD L2 merges partial lines — this replaces the ws
//   round-trip + transpose kernel (~108us) with ~15us of scattered stores.

constexpr int LVLS = 16;
constexpr unsigned TBL = 1u << 19;
constexpr unsigned TMASK = TBL - 1u;
constexpr unsigned P1 = 2654435761u;
constexpr unsigned P2 = 805459861u;
constexpr int PTS_PER_BLOCK = 512;   // 256 threads x 2 points

struct ResArr { float r[LVLS]; };

__global__ __launch_bounds__(256) void ingp_fused(
    const float* __restrict__ pts,
    const float* __restrict__ tables,
    float2* __restrict__ out,     // [N][LVLS] float2
    ResArr ra, int npts, int bpl)
{
    __shared__ float s_res[LVLS];
    if (threadIdx.x < LVLS) s_res[threadIdx.x] = ra.r[threadIdx.x];
    __syncthreads();

    int b = blockIdx.x;
    int phase_blocks = 8 * bpl;
    int xcd = b & 7;
    int phase = b / phase_blocks;
    int lvl = phase == 0 ? xcd : 15 - xcd;   // balanced pairing (k, 15-k)
    int q = (b % phase_blocks) >> 3;
    int t = threadIdx.x;

    float r = s_res[lvl];
    const float2* __restrict__ tab = (const float2*)tables + (size_t)lvl * TBL;

    int p[2];
    p[0] = q * PTS_PER_BLOCK + t;
    p[1] = p[0] + 256;

    unsigned idx[2][8];
    float w[2][8];
    bool valid[2];

    #pragma unroll
    for (int s = 0; s < 2; ++s) {
        valid[s] = p[s] < npts;
        int pp = valid[s] ? p[s] : 0;
        // nt: point stream must not evict the pinned table from L2
        float px = __builtin_nontemporal_load(pts + pp * 3 + 0);
        float py = __builtin_nontemporal_load(pts + pp * 3 + 1);
        float pz = __builtin_nontemporal_load(pts + pp * 3 + 2);
        float x = (px + 1.0f) * 0.5f;
        float y = (py + 1.0f) * 0.5f;
        float z = (pz + 1.0f) * 0.5f;
        float posx = x * r, posy = y * r, posz = z * r;
        float fx = floorf(posx), fy = floorf(posy), fz = floorf(posz);
        float wx = posx - fx, wy = posy - fy, wz = posz - fz;
        unsigned ix = (unsigned)fx, iy = (unsigned)fy, iz = (unsigned)fz;
        unsigned hx0 = ix,      hx1 = ix + 1u;
        unsigned hy0 = iy * P1, hy1 = hy0 + P1;
        unsigned hz0 = iz * P2, hz1 = hz0 + P2;
        idx[s][0] = (hx0 ^ hy0 ^ hz0) & TMASK;
        idx[s][1] = (hx0 ^ hy0 ^ hz1) & TMASK;
        idx[s][2] = (hx0 ^ hy1 ^ hz0) & TMASK;
        idx[s][3] = (hx0 ^ hy1 ^ hz1) & TMASK;
        idx[s][4] = (hx1 ^ hy0 ^ hz0) & TMASK;
        idx[s][5] = (hx1 ^ hy0 ^ hz1) & TMASK;
        idx[s][6] = (hx1 ^ hy1 ^ hz0) & TMASK;
        idx[s][7] = (hx1 ^ hy1 ^ hz1) & TMASK;
        float ox = 1.0f - wx, oy = 1.0f - wy, oz = 1.0f - wz;
        w[s][0] = (ox * oy) * oz;
        w[s][1] = (ox * oy) * wz;
        w[s][2] = (ox * wy) * oz;
        w[s][3] = (ox * wy) * wz;
        w[s][4] = (wx * oy) * oz;
        w[s][5] = (wx * oy) * wz;
        w[s][6] = (wx * wy) * oz;
        w[s][7] = (wx * wy) * wz;
    }

    // 16 independent gathers in flight before any use (L1 + pinned L2).
    float2 v[2][8];
    #pragma unroll
    for (int s = 0; s < 2; ++s)
        #pragma unroll
        for (int c = 0; c < 8; ++c)
            v[s][c] = tab[idx[s][c]];

    #pragma unroll
    for (int s = 0; s < 2; ++s) {
        float f0 = w[s][0] * v[s][0].x;
        float f1 = w[s][0] * v[s][0].y;
        #pragma unroll
        for (int c = 1; c < 8; ++c) {
            f0 += w[s][c] * v[s][c].x;
            f1 += w[s][c] * v[s][c].y;
        }
        // Direct strided store; L2 merges the partial lines (plain store —
        // nt here would force 8B partial-line HBM writes).
        if (valid[s])
            out[(size_t)p[s] * LVLS + lvl] = make_float2(f0, f1);
    }
}

extern "C" void kernel_launch(void* const* d_in, const int* in_sizes, int n_in,
                              void* d_out, int out_size, void* d_ws, size_t ws_size,
                              hipStream_t stream) {
    const float* pts    = (const float*)d_in[0];
    const float* tables = (const float*)d_in[1];
    int npts = in_sizes[0] / 3;

    // numpy-bitwise RES: GROWTH = exp((log(2048)-log(16))/15); floor(16*G**l)
    ResArr ra;
    double growth = exp((log(2048.0) - log(16.0)) / 15.0);
    for (int l = 0; l < LVLS; ++l)
        ra.r[l] = (float)floor(16.0 * pow(growth, (double)l));

    int bpl = (npts + PTS_PER_BLOCK - 1) / PTS_PER_BLOCK;
    int grid = LVLS * bpl;

    hipLaunchKernelGGL(ingp_fused, dim3(grid), dim3(256), 0, stream,
                       pts, tables, (float2*)d_out, ra, npts, bpl);
}

// Round 6
// 314.066 us; speedup vs baseline: 1.7339x; 1.7339x over previous
//
#include <hip/hip_runtime.h>
#include <cmath>

// INGP hashgrid encode, two-kernel (R3 structure) + x-pair merged gathers.
//   Gather: level pinned per XCD (blockIdx%8; phase2 lvl=15-k) -> XCD's 4MiB
//   L2 holds its level's table. Bound = L2 line-request throughput, so we
//   REDUCE requests: corners (0,j,k)/(1,j,k) have idx h and h^1 when ix is
//   even (x-prime=1) -> one aligned float4 load covers both (8->6 avg
//   requests per point-level). R5 lesson: cross-XCD partial-line output
//   stores are catastrophic -> keep level-major ws + LDS-tile transpose.

constexpr int LVLS = 16;
constexpr unsigned TBL = 1u << 19;
constexpr unsigned TMASK = TBL - 1u;
constexpr unsigned P1 = 2654435761u;
constexpr unsigned P2 = 805459861u;
constexpr int PTS_PER_BLOCK = 512;   // 256 threads x 2 points

typedef float vf2 __attribute__((ext_vector_type(2)));
typedef float vf4 __attribute__((ext_vector_type(4)));

struct ResArr { float r[LVLS]; };

template<bool USE_WS>
__global__ __launch_bounds__(256) void ingp_gather(
    const float* __restrict__ pts,
    const float* __restrict__ tables,
    float2* __restrict__ dst,     // USE_WS: [L][N] float2 ; else [N][L] float2
    ResArr ra, int npts, int bpl)
{
    __shared__ float s_res[LVLS];
    if (threadIdx.x < LVLS) s_res[threadIdx.x] = ra.r[threadIdx.x];
    __syncthreads();

    int b = blockIdx.x;
    int phase_blocks = 8 * bpl;
    int xcd = b & 7;
    int phase = b / phase_blocks;
    int lvl = phase == 0 ? xcd : 15 - xcd;   // balanced pairing (k, 15-k)
    int q = (b % phase_blocks) >> 3;
    int t = threadIdx.x;

    float r = s_res[lvl];
    const float2* __restrict__ tab = (const float2*)tables + (size_t)lvl * TBL;

    int p[2];
    p[0] = q * PTS_PER_BLOCK + t;
    p[1] = p[0] + 256;

    #pragma unroll
    for (int s = 0; s < 2; ++s) {
        bool valid = p[s] < npts;
        int pp = valid ? p[s] : 0;
        float px = __builtin_nontemporal_load(pts + pp * 3 + 0);
        float py = __builtin_nontemporal_load(pts + pp * 3 + 1);
        float pz = __builtin_nontemporal_load(pts + pp * 3 + 2);
        float x = (px + 1.0f) * 0.5f;
        float y = (py + 1.0f) * 0.5f;
        float z = (pz + 1.0f) * 0.5f;
        float posx = x * r, posy = y * r, posz = z * r;
        float fx = floorf(posx), fy = floorf(posy), fz = floorf(posz);
        float wx = posx - fx, wy = posy - fy, wz = posz - fz;
        unsigned ix = (unsigned)fx, iy = (unsigned)fy, iz = (unsigned)fz;
        unsigned hx0 = ix,      hx1 = ix + 1u;
        unsigned hy0 = iy * P1, hy1 = hy0 + P1;
        unsigned hz0 = iz * P2, hz1 = hz0 + P2;

        // yz-combination hashes (j,k): yz = j*2+k
        unsigned hyz[4];
        hyz[0] = hy0 ^ hz0;
        hyz[1] = hy0 ^ hz1;
        hyz[2] = hy1 ^ hz0;
        hyz[3] = hy1 ^ hz1;

        // v[i*4+yz]: corner (i,j,k)
        float2 v[8];
        if ((ix & 1u) == 0u) {
            // x-pair idx differ by ^1 -> one aligned float4 covers both.
            #pragma unroll
            for (int yz = 0; yz < 4; ++yz) {
                unsigned b0 = (hx0 ^ hyz[yz]) & TMASK;   // x=0 corner
                const vf4* lp = (const vf4*)(tab + (b0 & ~1u));
                vf4 qd = *lp;
                float2 lo = make_float2(qd.x, qd.y);
                float2 hi = make_float2(qd.z, qd.w);
                bool odd = (b0 & 1u) != 0u;
                v[yz]     = odd ? hi : lo;   // x=0 corner
                v[4 + yz] = odd ? lo : hi;   // x=1 corner (idx = b0^1)
            }
        } else {
            #pragma unroll
            for (int yz = 0; yz < 4; ++yz) {
                unsigned b0 = (hx0 ^ hyz[yz]) & TMASK;
                unsigned b1 = (hx1 ^ hyz[yz]) & TMASK;
                v[yz]     = tab[b0];
                v[4 + yz] = tab[b1];
            }
        }

        float ox = 1.0f - wx, oy = 1.0f - wy, oz = 1.0f - wz;
        float w[8];
        w[0] = (ox * oy) * oz;   // (0,0,0)
        w[1] = (ox * oy) * wz;   // (0,0,1)
        w[2] = (ox * wy) * oz;   // (0,1,0)
        w[3] = (ox * wy) * wz;   // (0,1,1)
        w[4] = (wx * oy) * oz;   // (1,0,0)
        w[5] = (wx * oy) * wz;   // (1,0,1)
        w[6] = (wx * wy) * oz;   // (1,1,0)
        w[7] = (wx * wy) * wz;   // (1,1,1)

        float f0 = w[0] * v[0].x;
        float f1 = w[0] * v[0].y;
        #pragma unroll
        for (int c = 1; c < 8; ++c) {
            f0 += w[c] * v[c].x;
            f1 += w[c] * v[c].y;
        }
        if (valid) {
            vf2 o; o.x = f0; o.y = f1;
            if (USE_WS)
                __builtin_nontemporal_store(o, (vf2*)(dst + (size_t)lvl * npts + p[s]));
            else
                dst[(size_t)p[s] * LVLS + lvl] = make_float2(f0, f1);
        }
    }
}

// ws [L][N] float2  ->  out [N][L] float2, all-coalesced via LDS tile.
__global__ __launch_bounds__(256) void ingp_transpose(
    const float2* __restrict__ ws, float4* __restrict__ out, int npts)
{
    __shared__ float2 a[LVLS][258];
    int base = blockIdx.x * 256;
    int t = threadIdx.x;

    #pragma unroll
    for (int l = 0; l < LVLS; ++l) {
        int pp = base + t;
        float2 val = make_float2(0.f, 0.f);
        if (pp < npts) {
            vf2 v = __builtin_nontemporal_load((const vf2*)(ws + (size_t)l * npts + pp));
            val = make_float2(v.x, v.y);
        }
        a[l][t] = val;
    }
    __syncthreads();

    int j = t & 7;
    int pl = t >> 3;
    #pragma unroll
    for (int it = 0; it < 8; ++it) {
        int pt = pl + it * 32;
        if (base + pt < npts) {
            float2 u = a[2 * j][pt];
            float2 v = a[2 * j + 1][pt];
            vf4 o; o.x = u.x; o.y = u.y; o.z = v.x; o.w = v.y;
            __builtin_nontemporal_store(o, (vf4*)(out + (size_t)(base + pt) * 8 + j));
        }
    }
}

extern "C" void kernel_launch(void* const* d_in, const int* in_sizes, int n_in,
                              void* d_out, int out_size, void* d_ws, size_t ws_size,
                              hipStream_t stream) {
    const float* pts    = (const float*)d_in[0];
    const float* tables = (const float*)d_in[1];
    int npts = in_sizes[0] / 3;

    // numpy-bitwise RES: GROWTH = exp((log(2048)-log(16))/15); floor(16*G**l)
    ResArr ra;
    double growth = exp((log(2048.0) - log(16.0)) / 15.0);
    for (int l = 0; l < LVLS; ++l)
        ra.r[l] = (float)floor(16.0 * pow(growth, (double)l));

    int bpl = (npts + PTS_PER_BLOCK - 1) / PTS_PER_BLOCK;
    int grid = LVLS * bpl;

    size_t ws_needed = (size_t)LVLS * npts * sizeof(float2);
    bool use_ws = ws_size >= ws_needed;

    if (use_ws) {
        float2* ws = (float2*)d_ws;
        hipLaunchKernelGGL(ingp_gather<true>, dim3(grid), dim3(256), 0, stream,
                           pts, tables, ws, ra, npts, bpl);
        hipLaunchKernelGGL(ingp_transpose, dim3((npts + 255) / 256), dim3(256), 0, stream,
                           ws, (float4*)d_out, npts);
    } else {
        hipLaunchKernelGGL(ingp_gather<false>, dim3(grid), dim3(256), 0, stream,
                           pts, tables, (float2*)d_out, ra, npts, bpl);
    }
}